// Round 5
// baseline (462.373 us; speedup 1.0000x reference)
//
#include <hip/hip_runtime.h>

#define IN_DIM  1024
#define OUT_DIM 4096
#define M_DIM   16384
#define QMAXF   127.0f

typedef int v4i __attribute__((ext_vector_type(4)));

// ---------------- column max of |in| over rows, float4-vectorized ----------------
__global__ void colmax4_kernel(const float4* __restrict__ in, unsigned* __restrict__ outb,
                               int rows, int rpb) {
    int t  = threadIdx.x;                       // 0..255
    int r0 = blockIdx.x * rpb;
    int r1 = r0 + rpb; if (r1 > rows) r1 = rows;
    float m0 = 0.f, m1 = 0.f, m2 = 0.f, m3 = 0.f;
    #pragma unroll 4
    for (int r = r0; r < r1; ++r) {
        float4 v = in[(size_t)r * 256 + t];
        m0 = fmaxf(m0, fabsf(v.x));
        m1 = fmaxf(m1, fabsf(v.y));
        m2 = fmaxf(m2, fabsf(v.z));
        m3 = fmaxf(m3, fabsf(v.w));
    }
    unsigned* o = outb + t * 4;
    atomicMax(o + 0, __float_as_uint(m0));      // nonneg floats: bit order == value order
    atomicMax(o + 1, __float_as_uint(m1));
    atomicMax(o + 2, __float_as_uint(m2));
    atomicMax(o + 3, __float_as_uint(m3));
}

// ---------------- scale[j] = act^0.5 / w^0.5 ; amax_w, amax_x via monotonicity ----------------
__global__ void scale_amax_kernel(float* __restrict__ wsf) {
    int j = threadIdx.x;                 // 0..1023
    float wsc = wsf[j];                  // w_scale
    float asc = wsf[1024 + j];           // act_scale
    float s = sqrtf(asc) / sqrtf(wsc);
    if (s == 0.0f) s = 1.0f;
    wsf[2048 + j] = s;
    float aw = wsc * s;                  // max_i fl(|w_ij|*s_j) == fl(w_scale_j*s_j)
    float ax = asc / s;                  // max_i fl(|x_ij|/s_j) == fl(act_scale_j/s_j)
    int lane = j & 63, wid = j >> 6;
    #pragma unroll
    for (int off = 32; off; off >>= 1) {
        aw = fmaxf(aw, __shfl_down(aw, off));
        ax = fmaxf(ax, __shfl_down(ax, off));
    }
    __shared__ float rw[16], rx[16];
    if (lane == 0) { rw[wid] = aw; rx[wid] = ax; }
    __syncthreads();
    if (j == 0) {
        float mw = rw[0], mx = rx[0];
        #pragma unroll
        for (int i = 1; i < 16; ++i) { mw = fmaxf(mw, rw[i]); mx = fmaxf(mx, rx[i]); }
        wsf[3072] = mw;
        wsf[3073] = mx;
    }
}

// ---------------- fused quantize W (mul scale) + X (div scale) to int8 ----------------
#define NW4 (OUT_DIM * IN_DIM / 4)
#define NX4 (M_DIM * IN_DIM / 4)

__device__ __forceinline__ unsigned pack_q4(float t0, float t1, float t2, float t3, float qs) {
    int q0 = (int)fminf(fmaxf(rintf(t0 / qs), -QMAXF), QMAXF);
    int q1 = (int)fminf(fmaxf(rintf(t1 / qs), -QMAXF), QMAXF);
    int q2 = (int)fminf(fmaxf(rintf(t2 / qs), -QMAXF), QMAXF);
    int q3 = (int)fminf(fmaxf(rintf(t3 / qs), -QMAXF), QMAXF);
    return (q0 & 0xff) | ((q1 & 0xff) << 8) | ((q2 & 0xff) << 16) | ((q3 & 0xff) << 24);
}

__global__ void quant_fused_kernel(const float4* __restrict__ w, const float4* __restrict__ x,
                                   const float* __restrict__ wsf,
                                   unsigned* __restrict__ w8, unsigned* __restrict__ x8) {
    const float4* scale4 = (const float4*)(wsf + 2048);
    float amw = wsf[3072], amx = wsf[3073];
    float qsw = amw > 0.f ? amw / QMAXF : 1.0f;
    float qsx = amx > 0.f ? amx / QMAXF : 1.0f;
    int stride = gridDim.x * blockDim.x;
    for (int i = blockIdx.x * blockDim.x + threadIdx.x; i < NW4 + NX4; i += stride) {
        if (i < NW4) {
            float4 v = w[i];
            float4 s = scale4[i & 255];
            w8[i] = pack_q4(v.x * s.x, v.y * s.y, v.z * s.z, v.w * s.w, qsw);
        } else {
            int k = i - NW4;
            float4 v = x[k];
            float4 s = scale4[k & 255];
            x8[k] = pack_q4(v.x / s.x, v.y / s.y, v.z / s.z, v.w / s.w, qsx);
        }
    }
}

// ---------------- 256x256 8-wave deep-pipelined int8 GEMM ----------------
// T1 (XCD swizzle) + T2 (LDS XOR swizzle) + T3/T4 (phase split, counted vmcnt,
// raw s_barrier) + T5 (setprio). 4-deep circular LDS buffer, stage 2 tiles ahead.
#define GBM 256
#define GBN 256
#define GBK 64
#define GNT (IN_DIM / GBK)   // 16 K-tiles

__device__ __forceinline__ void load_lds16(const void* g, void* l) {
    __builtin_amdgcn_global_load_lds((const __attribute__((address_space(1))) void*)g,
                                     (__attribute__((address_space(3))) void*)l, 16, 0, 0);
}

#define MFMA_I8 __builtin_amdgcn_mfma_i32_16x16x64_i8
#define FENCE() asm volatile("" ::: "memory")

__global__ __launch_bounds__(512, 2) void gemm_i8_256(
    const char* __restrict__ Xq, const char* __restrict__ Wq,
    const float* __restrict__ bias, const float* __restrict__ wsf,
    float* __restrict__ out) {
    __shared__ char sA[4][GBM * GBK];   // 4 x 16 KB
    __shared__ char sB[4][GBN * GBK];   // 4 x 16 KB  -> 128 KB total, 1 block/CU
    const int K = IN_DIM, N = OUT_DIM;
    int tid  = threadIdx.x;
    int lane = tid & 63, w = tid >> 6;
    int l15  = lane & 15, l4 = lane >> 4;

    // XCD-aware bijective swizzle: nwg = 16*64 = 1024, 1024 % 8 == 0
    int lin = blockIdx.y * gridDim.x + blockIdx.x;
    int swz = (lin & 7) * 128 + (lin >> 3);
    int bn0 = (swz & 15) * GBN;
    int bm0 = (swz >> 4) * GBM;

    int wm = w >> 2, wn = w & 3;        // wave grid 2(M) x 4(N); per-wave out 128x64

    // ---- staging geometry: per tile per matrix = 1024 chunks of 16B, 2/thread ----
    // chunk = w*128 + i*64 + lane; row = chunk>>2; slot = chunk&3
    // source col pre-swizzled, LDS dest linear (both-sides involution)
    size_t srcA[2], srcB[2];
    int dstOff[2];
    #pragma unroll
    for (int i = 0; i < 2; ++i) {
        int chunk = w * 128 + i * 64 + lane;
        int row = chunk >> 2, slot = chunk & 3;
        int col = (slot * 16) ^ ((row & 3) << 4);
        srcA[i]   = (size_t)(bm0 + row) * K + col;
        srcB[i]   = (size_t)(bn0 + row) * K + col;
        dstOff[i] = (w * 128 + i * 64) * 16;
    }

    // ---- ds_read bases: row*64 + (l4*16 ^ ((row&3)<<4)); row&3 == l15&3 ----
    int xorv  = ((l4 ^ (l15 & 3)) << 4);
    int aBase = (wm * 128 + l15) * 64 + xorv;
    int bBase = (wn * 64  + l15) * 64 + xorv;

    v4i acc[8][4];
    #pragma unroll
    for (int i = 0; i < 8; ++i)
        #pragma unroll
        for (int j = 0; j < 4; ++j)
            acc[i][j] = (v4i){0, 0, 0, 0};

    // ---- prologue: stage tiles 0 and 1 (8 loads/thread), wait tile 0 (vmcnt 4) ----
    #pragma unroll
    for (int tt = 0; tt < 2; ++tt) {
        #pragma unroll
        for (int i = 0; i < 2; ++i) load_lds16(Xq + srcA[i] + tt * GBK, sA[tt] + dstOff[i]);
        #pragma unroll
        for (int i = 0; i < 2; ++i) load_lds16(Wq + srcB[i] + tt * GBK, sB[tt] + dstOff[i]);
    }
    asm volatile("s_waitcnt vmcnt(4)");
    __builtin_amdgcn_s_barrier();
    FENCE();

    for (int t = 0; t < GNT; ++t) {
        const int rb = t & 3, sb = (t + 2) & 3;
        const char* A = sA[rb];
        const char* B = sB[rb];
        const bool st = (t + 2 < GNT);
        v4i a[4], b[4];

        // ---- phase 0: read A-frags m0-3 + B-frags; stage A(t+2); MFMA quadrant ----
        #pragma unroll
        for (int i = 0; i < 4; ++i) a[i] = *(const v4i*)(A + aBase + (i * 16) * 64);
        #pragma unroll
        for (int i = 0; i < 4; ++i) b[i] = *(const v4i*)(B + bBase + i * 1024);
        if (st) {
            load_lds16(Xq + srcA[0] + (t + 2) * GBK, sA[sb] + dstOff[0]);
            load_lds16(Xq + srcA[1] + (t + 2) * GBK, sA[sb] + dstOff[1]);
        }
        __builtin_amdgcn_s_barrier();
        FENCE();
        __builtin_amdgcn_s_setprio(1);
        #pragma unroll
        for (int am = 0; am < 4; ++am)
            #pragma unroll
            for (int bn = 0; bn < 4; ++bn)
                acc[am][bn] = MFMA_I8(a[am], b[bn], acc[am][bn], 0, 0, 0);
        __builtin_amdgcn_s_setprio(0);
        __builtin_amdgcn_s_barrier();
        FENCE();

        // ---- phase 1: read A-frags m4-7; stage B(t+2); MFMA quadrant; counted wait ----
        #pragma unroll
        for (int i = 0; i < 4; ++i) a[i] = *(const v4i*)(A + aBase + (64 + i * 16) * 64);
        if (st) {
            load_lds16(Wq + srcB[0] + (t + 2) * GBK, sB[sb] + dstOff[0]);
            load_lds16(Wq + srcB[1] + (t + 2) * GBK, sB[sb] + dstOff[1]);
        }
        __builtin_amdgcn_s_barrier();
        FENCE();
        __builtin_amdgcn_s_setprio(1);
        #pragma unroll
        for (int am = 0; am < 4; ++am)
            #pragma unroll
            for (int bn = 0; bn < 4; ++bn)
                acc[4 + am][bn] = MFMA_I8(a[am], b[bn], acc[4 + am][bn], 0, 0, 0);
        __builtin_amdgcn_s_setprio(0);
        // vmcnt ledger: outstanding = tile t+2's 4 loads -> vmcnt(4) proves t+1 landed
        if (t < GNT - 2)       asm volatile("s_waitcnt vmcnt(4)");
        else if (t == GNT - 2) asm volatile("s_waitcnt vmcnt(0)");
        __builtin_amdgcn_s_barrier();
        FENCE();
    }

    // ---- epilogue: dequant + bias, write C ----
    float amw = wsf[3072], amx = wsf[3073];
    float sw = amw > 0.f ? amw / QMAXF : 1.0f;
    float sx = amx > 0.f ? amx / QMAXF : 1.0f;
    float sp = sw * sx;

    #pragma unroll
    for (int am = 0; am < 8; ++am) {
        int row = bm0 + wm * 128 + am * 16 + l4 * 4;
        #pragma unroll
        for (int bn = 0; bn < 4; ++bn) {
            int col = bn0 + wn * 64 + bn * 16 + l15;
            float bv = bias[col];
            #pragma unroll
            for (int r = 0; r < 4; ++r)
                out[(size_t)(row + r) * N + col] = fmaf(sp, (float)acc[am][bn][r], bv);
        }
    }
}

// ---------------- host ----------------
extern "C" void kernel_launch(void* const* d_in, const int* in_sizes, int n_in,
                              void* d_out, int out_size, void* d_ws, size_t ws_size,
                              hipStream_t stream) {
    const float* x      = (const float*)d_in[0];   // [16384, 1024]
    const float* weight = (const float*)d_in[1];   // [4096, 1024]
    const float* bias   = (const float*)d_in[2];   // [4096]
    float* out = (float*)d_out;

    float*    wsf = (float*)d_ws;
    unsigned* wsu = (unsigned*)d_ws;
    char* X8 = (char*)d_ws + 16384;                      // 16 MB
    char* W8 = X8 + (size_t)M_DIM * IN_DIM;              // 4 MB

    hipMemsetAsync(d_ws, 0, 16384, stream);

    colmax4_kernel<<<256, 256, 0, stream>>>((const float4*)weight, wsu,        OUT_DIM, 16);
    colmax4_kernel<<<256, 256, 0, stream>>>((const float4*)x,      wsu + 1024, M_DIM,   64);

    scale_amax_kernel<<<1, 1024, 0, stream>>>(wsf);

    quant_fused_kernel<<<2560, 256, 0, stream>>>((const float4*)weight, (const float4*)x,
                                                 wsf, (unsigned*)W8, (unsigned*)X8);

    gemm_i8_256<<<dim3(OUT_DIM / GBN, M_DIM / GBM), 512, 0, stream>>>(X8, W8, bias, wsf, out);
}